// Round 3
// baseline (274.629 us; speedup 1.0000x reference)
//
#include <hip/hip_runtime.h>

// EdgeSageLayer on MI355X — round 10.
// agg[n] = (sum_{e:dst=n} concat(x[src_e], ea_e)) @ msg_w / deg + msg_b*(deg>0)
// R9 postmortem: in-kernel matmul made agg_fused LDS-PIPE-bound at the CU
// level: 560 LDS instr/pair (36 gather bpermute + 40 reduce + 480 matmul
// w/scratch reads) x ~4cyc = 2200 cyc/pair/CU == measured 89.7us. The LDS
// pipe is per-CU shared; wave overlap cannot hide it (VALU 36%, HBM 21%).
// R10: split again. Aggregate reverts to the proven R8 form (~55us,
// memory-latency bound, 76 LDS ops/pair). Finalize rebuilt as finalize_v3:
// weights resident in VGPRs (160/lane, column-per-lane), inputs vector-
// loaded into lanes 0-15/0-7 and broadcast via v_readlane (VALU pipe, ZERO
// LDS) instead of the old serial uniform-load chain. 2 nodes/iter for VMEM
// pipelining; 2 waves/SIMD. Model: ~640 VALU cyc/node -> ~13us VALU floor,
// 45MB mostly-L3 input -> ~7us mem floor.

constexpr int N_NODES  = 50000;
constexpr int N_EDGES  = 800000;
constexpr int IN_DIM   = 64;
constexpr int EDGE_DIM = 32;
constexpr int OUT_DIM  = 64;
constexpr int CAP      = 48;      // bucket capacity; Poisson(16) max deg ~40
constexpr int OVF_CAP  = 65536;   // overflow list capacity (deg>CAP tails)

using vf4 = __attribute__((ext_vector_type(4))) float;
using vi2 = __attribute__((ext_vector_type(2))) int;

__device__ __forceinline__ float rl(float v, int srclane) {
    return __int_as_float(__builtin_amdgcn_readlane(__float_as_int(v), srclane));
}

// ---------------------------------------------------------------------------
// K1: single-pass bucket build. pos = atomicAdd(cnt[dst]); write (e,src).
// Rare pos>=CAP goes to the overflow list.
// ---------------------------------------------------------------------------
__device__ __forceinline__ void place_one(int dst, int e, int src,
                                          int* cnt, int2* buckets,
                                          int4* ovf, int* ovf_cur) {
    const int pos = atomicAdd(&cnt[dst], 1);
    if (pos < CAP) {
        buckets[(size_t)dst * CAP + pos] = make_int2(e, src);
    } else {
        const int o = atomicAdd(ovf_cur, 1);
        if (o < OVF_CAP) ovf[o] = make_int4(dst, e, src, 0);
    }
}

__global__ __launch_bounds__(256) void place_bucket_k(
    const int* __restrict__ ei, int* cnt, int2* __restrict__ buckets,
    int4* __restrict__ ovf, int* ovf_cur)
{
    const int t = blockIdx.x * 256 + threadIdx.x;
    if (t * 4 + 3 < N_EDGES) {
        const int4 d4 = ((const int4*)(ei + N_EDGES))[t];
        const int4 s4 = ((const int4*)ei)[t];
        place_one(d4.x, 4 * t + 0, s4.x, cnt, buckets, ovf, ovf_cur);
        place_one(d4.y, 4 * t + 1, s4.y, cnt, buckets, ovf, ovf_cur);
        place_one(d4.z, 4 * t + 2, s4.z, cnt, buckets, ovf, ovf_cur);
        place_one(d4.w, 4 * t + 3, s4.w, cnt, buckets, ovf, ovf_cur);
    } else {
        for (int e = t * 4; e < min(t * 4 + 4, N_EDGES); ++e)
            place_one(ei[N_EDGES + e], e, ei[e], cnt, buckets, ovf, ovf_cur);
    }
}

// ---------------------------------------------------------------------------
// K2 (R8 proven form): gather-reduce, 2 nodes/wave, deep-MLP inner loop.
// 16 edges/iter: 12 gathers issued into zero-init masked temps before any
// accumulate. ea + bucket loads nontemporal. shfl_xor reduce; float4 stores
// zero-fill deg==0 rows. cnt>CAP nodes scan the tiny overflow list.
// ---------------------------------------------------------------------------
__global__ __launch_bounds__(256) void aggregate_bucket_k(
    const float* __restrict__ x, const float* __restrict__ ea,
    const int2* __restrict__ buckets, const int* __restrict__ cnt,
    const int4* __restrict__ ovf, const int* __restrict__ ovf_cur,
    float* __restrict__ sum_x, float* __restrict__ sum_ea)
{
    const int lane   = threadIdx.x & 63;
    const int wave   = (blockIdx.x * blockDim.x + threadIdx.x) >> 6;
    const int nwaves = (gridDim.x * blockDim.x) >> 6;

    const int grpx = lane >> 4, colx = lane & 15;  // x: 4 edges/step
    const int grpe = lane >> 3, cole = lane & 7;   // ea: 8 edges/step

    for (int n0 = wave * 2; n0 < N_NODES; n0 += nwaves * 2) {
        const int  nA   = __builtin_amdgcn_readfirstlane(n0);
        const bool hasB = (n0 + 1 < N_NODES);
        const int  nB   = nA + 1;

        const int cFA = __builtin_amdgcn_readfirstlane(cnt[nA]);
        const int cFB = hasB ? __builtin_amdgcn_readfirstlane(cnt[nB]) : 0;
        const int cA  = min(cFA, CAP);
        const int cB  = min(cFB, CAP);

        int eA = 0, srcA = 0, eB = 0, srcB = 0;
        if (lane < cA) {
            const vi2 p = __builtin_nontemporal_load(
                (const vi2*)buckets + (size_t)nA * CAP + lane);
            eA = p.x; srcA = p.y;
        }
        if (lane < cB) {
            const vi2 p = __builtin_nontemporal_load(
                (const vi2*)buckets + (size_t)nB * CAP + lane);
            eB = p.x; srcB = p.y;
        }

        vf4 axA = {0,0,0,0}, aeA = {0,0,0,0};
        vf4 axB = {0,0,0,0}, aeB = {0,0,0,0};

        const int mMax = max(cA, cB);
        for (int j = 0; j < mMax; j += 16) {
            const int jx0 = j +  0 + grpx, jx1 = j +  4 + grpx;
            const int jx2 = j +  8 + grpx, jx3 = j + 12 + grpx;
            const int je0 = j +  0 + grpe, je1 = j +  8 + grpe;
            // max shuffled lane index 47 < 64; lanes >= cnt hold 0 -> valid.
            const int sA0 = __shfl(srcA, jx0), sA1 = __shfl(srcA, jx1);
            const int sA2 = __shfl(srcA, jx2), sA3 = __shfl(srcA, jx3);
            const int sB0 = __shfl(srcB, jx0), sB1 = __shfl(srcB, jx1);
            const int sB2 = __shfl(srcB, jx2), sB3 = __shfl(srcB, jx3);
            const int fA0 = __shfl(eA, je0),   fA1 = __shfl(eA, je1);
            const int fB0 = __shfl(eB, je0),   fB1 = __shfl(eB, je1);

            vf4 xA0 = {0,0,0,0}, xA1 = {0,0,0,0}, xA2 = {0,0,0,0}, xA3 = {0,0,0,0};
            vf4 xB0 = {0,0,0,0}, xB1 = {0,0,0,0}, xB2 = {0,0,0,0}, xB3 = {0,0,0,0};
            vf4 eA0v = {0,0,0,0}, eA1v = {0,0,0,0};
            vf4 eB0v = {0,0,0,0}, eB1v = {0,0,0,0};

            // all 12 loads issue before any accumulate (independent temps)
            if (jx0 < cA) xA0 = ((const vf4*)(x + (size_t)sA0 * IN_DIM))[colx];
            if (jx1 < cA) xA1 = ((const vf4*)(x + (size_t)sA1 * IN_DIM))[colx];
            if (jx2 < cA) xA2 = ((const vf4*)(x + (size_t)sA2 * IN_DIM))[colx];
            if (jx3 < cA) xA3 = ((const vf4*)(x + (size_t)sA3 * IN_DIM))[colx];
            if (jx0 < cB) xB0 = ((const vf4*)(x + (size_t)sB0 * IN_DIM))[colx];
            if (jx1 < cB) xB1 = ((const vf4*)(x + (size_t)sB1 * IN_DIM))[colx];
            if (jx2 < cB) xB2 = ((const vf4*)(x + (size_t)sB2 * IN_DIM))[colx];
            if (jx3 < cB) xB3 = ((const vf4*)(x + (size_t)sB3 * IN_DIM))[colx];
            if (je0 < cA) eA0v = __builtin_nontemporal_load(
                (const vf4*)(ea + (size_t)fA0 * EDGE_DIM) + cole);
            if (je1 < cA) eA1v = __builtin_nontemporal_load(
                (const vf4*)(ea + (size_t)fA1 * EDGE_DIM) + cole);
            if (je0 < cB) eB0v = __builtin_nontemporal_load(
                (const vf4*)(ea + (size_t)fB0 * EDGE_DIM) + cole);
            if (je1 < cB) eB1v = __builtin_nontemporal_load(
                (const vf4*)(ea + (size_t)fB1 * EDGE_DIM) + cole);

            axA += (xA0 + xA1) + (xA2 + xA3);
            axB += (xB0 + xB1) + (xB2 + xB3);
            aeA += eA0v + eA1v;
            aeB += eB0v + eB1v;
        }

        // rare: overflow entries (deg > CAP). Group 0 accumulates pre-reduce.
        if (cFA > CAP || cFB > CAP) {
            const int novf = min(__builtin_amdgcn_readfirstlane(*ovf_cur), OVF_CAP);
            for (int i = 0; i < novf; ++i) {
                const int4 v = ovf[i];
                const bool mA = (v.x == nA), mB = hasB && (v.x == nB);
                if (mA || mB) {
                    if (grpx == 0) {
                        const vf4 t = ((const vf4*)(x + (size_t)v.z * IN_DIM))[colx];
                        if (mA) axA += t; else axB += t;
                    }
                    if (grpe == 0) {
                        const vf4 t = ((const vf4*)(ea + (size_t)v.y * EDGE_DIM))[cole];
                        if (mA) aeA += t; else aeB += t;
                    }
                }
            }
        }

#pragma unroll
        for (int mask = 16; mask < 64; mask <<= 1) {
            axA.x += __shfl_xor(axA.x, mask); axA.y += __shfl_xor(axA.y, mask);
            axA.z += __shfl_xor(axA.z, mask); axA.w += __shfl_xor(axA.w, mask);
            axB.x += __shfl_xor(axB.x, mask); axB.y += __shfl_xor(axB.y, mask);
            axB.z += __shfl_xor(axB.z, mask); axB.w += __shfl_xor(axB.w, mask);
        }
#pragma unroll
        for (int mask = 8; mask < 64; mask <<= 1) {
            aeA.x += __shfl_xor(aeA.x, mask); aeA.y += __shfl_xor(aeA.y, mask);
            aeA.z += __shfl_xor(aeA.z, mask); aeA.w += __shfl_xor(aeA.w, mask);
            aeB.x += __shfl_xor(aeB.x, mask); aeB.y += __shfl_xor(aeB.y, mask);
            aeB.z += __shfl_xor(aeB.z, mask); aeB.w += __shfl_xor(aeB.w, mask);
        }

        if (lane < 16) ((vf4*)(sum_x + (size_t)nA * IN_DIM))[lane] = axA;
        if (lane < 8)  ((vf4*)(sum_ea + (size_t)nA * EDGE_DIM))[lane] = aeA;
        if (hasB) {
            if (lane < 16) ((vf4*)(sum_x + (size_t)nB * IN_DIM))[lane] = axB;
            if (lane < 8)  ((vf4*)(sum_ea + (size_t)nB * EDGE_DIM))[lane] = aeB;
        }
    }
}

// ---------------------------------------------------------------------------
// K3 (R10): finalize_v3. Weights resident in VGPRs (column-per-lane, 160).
// Inputs vector-loaded into lanes 0-15 (sum_x, x) / 0-7 (sum_ea) and
// broadcast per-k via v_readlane — VALU pipe, ZERO LDS (the old finalize64
// was a serial uniform-load chain; R9's LDS broadcast hit the shared pipe).
// 2 nodes/iter -> 6 VMEM loads in flight. 2 waves/SIMD (VGPR ~200).
// sum_x_in aliases out; each row read then written by exactly one wave.
// ---------------------------------------------------------------------------
__global__ __launch_bounds__(256, 2) void finalize_v3_k(
    const float* __restrict__ x, const float* sum_x_in,
    const float* __restrict__ sum_ea, const int* __restrict__ cnt,
    const float* __restrict__ msg_w, const float* __restrict__ msg_b,
    const float* __restrict__ self_w, const float* __restrict__ self_b,
    float* out)
{
    const int lane = threadIdx.x & 63;               // output column c
    const int wid  = blockIdx.x * 4 + (threadIdx.x >> 6);
    const int nw   = gridDim.x * 4;

    float wm[96];   // msg_w column `lane`
    float wsf[64];  // self_w column `lane`
#pragma unroll
    for (int k = 0; k < 96; ++k) wm[k] = msg_w[k * OUT_DIM + lane];
#pragma unroll
    for (int k = 0; k < 64; ++k) wsf[k] = self_w[k * OUT_DIM + lane];
    const float mb = msg_b[lane];
    const float sb = self_b[lane];

    for (int n0 = wid * 2; n0 < N_NODES; n0 += nw * 2) {
        const int  nA   = __builtin_amdgcn_readfirstlane(n0);
        const bool hasB = (n0 + 1 < N_NODES);
        const int  nB   = nA + 1;

        // all input rows vector-loaded up front (6 independent VMEM ops)
        vf4 r1A = {0,0,0,0}, r2A = {0,0,0,0}, r3A = {0,0,0,0};
        vf4 r1B = {0,0,0,0}, r2B = {0,0,0,0}, r3B = {0,0,0,0};
        if (lane < 16) {
            r1A = ((const vf4*)(sum_x_in + (size_t)nA * IN_DIM))[lane];
            r3A = ((const vf4*)(x        + (size_t)nA * IN_DIM))[lane];
        }
        if (lane < 8) r2A = ((const vf4*)(sum_ea + (size_t)nA * EDGE_DIM))[lane];
        if (hasB) {
            if (lane < 16) {
                r1B = ((const vf4*)(sum_x_in + (size_t)nB * IN_DIM))[lane];
                r3B = ((const vf4*)(x        + (size_t)nB * IN_DIM))[lane];
            }
            if (lane < 8) r2B = ((const vf4*)(sum_ea + (size_t)nB * EDGE_DIM))[lane];
        }
        const int dA = cnt[nA];                     // uniform -> scalar load
        const int dB = hasB ? cnt[nB] : 0;

        float amA0 = 0.f, amA1 = 0.f, amB0 = 0.f, amB1 = 0.f;
        float asA0 = 0.f, asA1 = 0.f, asB0 = 0.f, asB1 = 0.f;

        // sum_x part: k = 4q+i lives at lane q, component i
#pragma unroll
        for (int q = 0; q < 16; ++q) {
            amA0 = fmaf(rl(r1A[0], q), wm[4 * q + 0], amA0);
            amA1 = fmaf(rl(r1A[1], q), wm[4 * q + 1], amA1);
            amA0 = fmaf(rl(r1A[2], q), wm[4 * q + 2], amA0);
            amA1 = fmaf(rl(r1A[3], q), wm[4 * q + 3], amA1);
            amB0 = fmaf(rl(r1B[0], q), wm[4 * q + 0], amB0);
            amB1 = fmaf(rl(r1B[1], q), wm[4 * q + 1], amB1);
            amB0 = fmaf(rl(r1B[2], q), wm[4 * q + 2], amB0);
            amB1 = fmaf(rl(r1B[3], q), wm[4 * q + 3], amB1);
        }
        // sum_ea part: k = 64+4q+i at lane q, component i
#pragma unroll
        for (int q = 0; q < 8; ++q) {
            amA0 = fmaf(rl(r2A[0], q), wm[64 + 4 * q + 0], amA0);
            amA1 = fmaf(rl(r2A[1], q), wm[64 + 4 * q + 1], amA1);
            amA0 = fmaf(rl(r2A[2], q), wm[64 + 4 * q + 2], amA0);
            amA1 = fmaf(rl(r2A[3], q), wm[64 + 4 * q + 3], amA1);
            amB0 = fmaf(rl(r2B[0], q), wm[64 + 4 * q + 0], amB0);
            amB1 = fmaf(rl(r2B[1], q), wm[64 + 4 * q + 1], amB1);
            amB0 = fmaf(rl(r2B[2], q), wm[64 + 4 * q + 2], amB0);
            amB1 = fmaf(rl(r2B[3], q), wm[64 + 4 * q + 3], amB1);
        }
        // self part: x[n][4q+i] at lane q, component i
#pragma unroll
        for (int q = 0; q < 16; ++q) {
            asA0 = fmaf(rl(r3A[0], q), wsf[4 * q + 0], asA0);
            asA1 = fmaf(rl(r3A[1], q), wsf[4 * q + 1], asA1);
            asA0 = fmaf(rl(r3A[2], q), wsf[4 * q + 2], asA0);
            asA1 = fmaf(rl(r3A[3], q), wsf[4 * q + 3], asA1);
            asB0 = fmaf(rl(r3B[0], q), wsf[4 * q + 0], asB0);
            asB1 = fmaf(rl(r3B[1], q), wsf[4 * q + 1], asB1);
            asB0 = fmaf(rl(r3B[2], q), wsf[4 * q + 2], asB0);
            asB1 = fmaf(rl(r3B[3], q), wsf[4 * q + 3], asB1);
        }

        const float invA  = 1.0f / (float)max(dA, 1);
        const float bselA = (dA > 0) ? 1.0f : 0.0f;
        out[(size_t)nA * OUT_DIM + lane] =
            (asA0 + asA1) + sb + (amA0 + amA1) * invA + mb * bselA;
        if (hasB) {
            const float invB  = 1.0f / (float)max(dB, 1);
            const float bselB = (dB > 0) ? 1.0f : 0.0f;
            out[(size_t)nB * OUT_DIM + lane] =
                (asB0 + asB1) + sb + (amB0 + amB1) * invB + mb * bselB;
        }
    }
}

// ---------------------------------------------------------------------------
// Tier-3 fallback: atomic scatter (needs only ~6.6 MB ws).
// ---------------------------------------------------------------------------
__global__ __launch_bounds__(768) void scatter_fb_k(
    const float* __restrict__ x, const int* __restrict__ ei,
    const float* __restrict__ ea, float* sum_x, float* sum_ea, int* deg)
{
    const int t  = threadIdx.x;
    const int el = t / 96;
    const int k  = t - el * 96;
    const int e  = blockIdx.x * 8 + el;
    if (e >= N_EDGES) return;
    const int dst = ei[N_EDGES + e];
    if (k < IN_DIM) {
        const int src = ei[e];
        atomicAdd(&sum_x[dst * IN_DIM + k], x[src * IN_DIM + k]);
        if (k == 0) atomicAdd(&deg[dst], 1);
    } else {
        const int kk = k - IN_DIM;
        atomicAdd(&sum_ea[dst * EDGE_DIM + kk], ea[e * EDGE_DIM + kk]);
    }
}

// ---------------------------------------------------------------------------
extern "C" void kernel_launch(void* const* d_in, const int* in_sizes, int n_in,
                              void* d_out, int out_size, void* d_ws, size_t ws_size,
                              hipStream_t stream) {
    const float* x      = (const float*)d_in[0];
    const int*   ei     = (const int*)d_in[1];   // [2][E]
    const float* ea     = (const float*)d_in[2];
    const float* msg_w  = (const float*)d_in[3];
    const float* msg_b  = (const float*)d_in[4];
    const float* self_w = (const float*)d_in[5];
    const float* self_b = (const float*)d_in[6];

    float* out = (float*)d_out;  // doubles as sum_x accumulator

    // ws layout (ints unless noted):
    //   cnt[50000] | ovf_cur[1] | pad to 16 | buckets[50000*CAP int2]
    //   | ovf[OVF_CAP int4] | sum_ea[1.6M float]
    int*   cnt     = (int*)d_ws;
    int*   ovf_cur = cnt + N_NODES;
    int2*  buckets = (int2*)(cnt + N_NODES + 16);
    int4*  ovf     = (int4*)(buckets + (size_t)N_NODES * CAP);
    float* sum_ea  = (float*)(ovf + OVF_CAP);
    const size_t need_bucket =
        ((size_t)N_NODES + 16 + 2 * (size_t)N_NODES * CAP + 4 * (size_t)OVF_CAP +
         (size_t)N_NODES * EDGE_DIM) * sizeof(int);

    if (ws_size >= need_bucket) {
        hipMemsetAsync(cnt, 0, (N_NODES + 16) * sizeof(int), stream);
        place_bucket_k<<<(N_EDGES / 4 + 255) / 256, 256, 0, stream>>>(
            ei, cnt, buckets, ovf, ovf_cur);
        aggregate_bucket_k<<<(N_NODES / 2 + 3) / 4, 256, 0, stream>>>(
            x, ea, buckets, cnt, ovf, ovf_cur, out, sum_ea);
        finalize_v3_k<<<512, 256, 0, stream>>>(
            x, out, sum_ea, cnt, msg_w, msg_b, self_w, self_b, out);
    } else {
        // Fallback: fp32 atomic scatter (R1 path) + finalize_v3
        float* fb_sum_ea = (float*)d_ws;
        int*   deg       = (int*)(fb_sum_ea + (size_t)N_NODES * EDGE_DIM);
        hipMemsetAsync(d_out, 0, (size_t)N_NODES * OUT_DIM * sizeof(float), stream);
        hipMemsetAsync(d_ws, 0, (size_t)N_NODES * (EDGE_DIM + 1) * sizeof(float), stream);
        scatter_fb_k<<<(N_EDGES + 7) / 8, 768, 0, stream>>>(
            x, ei, ea, out, fb_sum_ea, deg);
        finalize_v3_k<<<512, 256, 0, stream>>>(
            x, out, fb_sum_ea, deg, msg_w, msg_b, self_w, self_b, out);
    }
}